// Round 1
// baseline (134.906 us; speedup 1.0000x reference)
//
#include <hip/hip_runtime.h>
#include <math.h>

// Neighborlist screening: gather -> diff -> norm -> (dummy & cutoff) mask.
// Outputs (flat float32 in d_out):
//   [0,   P)  : screened i0 as float (-1.0 if screened out)
//   [P,  2P)  : screened i1 as float
//   [2P, 3P)  : distances
//   [3P, 6P)  : diff_vectors, row-major [P][3]
#define CUTOFF_F 5.2f

__global__ __launch_bounds__(256) void nbr_screen_kernel(
    const int*   __restrict__ species,   // [N]
    const float* __restrict__ coords,    // [N*3]
    const int*   __restrict__ nbr,       // [2*P]
    const float* __restrict__ shift,     // [P*3]
    float*       __restrict__ out,       // [6*P]
    int P)
{
    const int t    = blockIdx.x * blockDim.x + threadIdx.x;
    const long base = (long)t * 4;
    if (base >= P) return;

    if (base + 4 <= P) {
        // ---- vectorized path: 4 pairs per thread, all 16B accesses ----
        const int4 i0v = *reinterpret_cast<const int4*>(nbr + base);
        const int4 i1v = *reinterpret_cast<const int4*>(nbr + (long)P + base);
        const float4* sv = reinterpret_cast<const float4*>(shift + base * 3);
        const float4 s0 = sv[0], s1 = sv[1], s2 = sv[2];

        const float sh[12] = {s0.x, s0.y, s0.z, s0.w,
                              s1.x, s1.y, s1.z, s1.w,
                              s2.x, s2.y, s2.z, s2.w};
        const int ia[4] = {i0v.x, i0v.y, i0v.z, i0v.w};
        const int ib[4] = {i1v.x, i1v.y, i1v.z, i1v.w};

        float oi0[4], oi1[4], od[4], dv[12];
        #pragma unroll
        for (int k = 0; k < 4; ++k) {
            const int a = ia[k], b = ib[k];
            const bool valid = (species[a] != -1) & (species[b] != -1);
            const float ax = coords[3l*a], ay = coords[3l*a+1], az = coords[3l*a+2];
            const float bx = coords[3l*b], by = coords[3l*b+1], bz = coords[3l*b+2];
            // (c0 - c1) + shift, left-to-right like the reference
            const float dx = (ax - bx) + sh[3*k];
            const float dy = (ay - by) + sh[3*k+1];
            const float dz = (az - bz) + sh[3*k+2];
            // block fma contraction: must bit-match numpy (x*x + y*y) + z*z
            const float d2 = __fadd_rn(__fadd_rn(__fmul_rn(dx, dx),
                                                 __fmul_rn(dy, dy)),
                                       __fmul_rn(dz, dz));
            const float dist = (d2 > 0.0f) ? sqrtf(d2) : 0.0f;
            const bool keep = valid && (dist <= CUTOFF_F);
            oi0[k] = keep ? (float)a : -1.0f;
            oi1[k] = keep ? (float)b : -1.0f;
            od[k]  = keep ? dist : 0.0f;
            dv[3*k]   = keep ? dx : 0.0f;
            dv[3*k+1] = keep ? dy : 0.0f;
            dv[3*k+2] = keep ? dz : 0.0f;
        }

        *reinterpret_cast<float4*>(out + base)               = make_float4(oi0[0], oi0[1], oi0[2], oi0[3]);
        *reinterpret_cast<float4*>(out + (long)P + base)     = make_float4(oi1[0], oi1[1], oi1[2], oi1[3]);
        *reinterpret_cast<float4*>(out + 2l*P + base)        = make_float4(od[0],  od[1],  od[2],  od[3]);
        float4* dvo = reinterpret_cast<float4*>(out + 3l*P + base*3);
        dvo[0] = make_float4(dv[0], dv[1], dv[2],  dv[3]);
        dvo[1] = make_float4(dv[4], dv[5], dv[6],  dv[7]);
        dvo[2] = make_float4(dv[8], dv[9], dv[10], dv[11]);
    } else {
        // ---- scalar tail (P % 4 != 0) ----
        for (long p = base; p < P; ++p) {
            const int a = nbr[p], b = nbr[(long)P + p];
            const bool valid = (species[a] != -1) & (species[b] != -1);
            const float ax = coords[3l*a], ay = coords[3l*a+1], az = coords[3l*a+2];
            const float bx = coords[3l*b], by = coords[3l*b+1], bz = coords[3l*b+2];
            const float dx = (ax - bx) + shift[p*3];
            const float dy = (ay - by) + shift[p*3+1];
            const float dz = (az - bz) + shift[p*3+2];
            const float d2 = __fadd_rn(__fadd_rn(__fmul_rn(dx, dx),
                                                 __fmul_rn(dy, dy)),
                                       __fmul_rn(dz, dz));
            const float dist = (d2 > 0.0f) ? sqrtf(d2) : 0.0f;
            const bool keep = valid && (dist <= CUTOFF_F);
            out[p]        = keep ? (float)a : -1.0f;
            out[(long)P+p]= keep ? (float)b : -1.0f;
            out[2l*P+p]   = keep ? dist : 0.0f;
            out[3l*P+p*3]   = keep ? dx : 0.0f;
            out[3l*P+p*3+1] = keep ? dy : 0.0f;
            out[3l*P+p*3+2] = keep ? dz : 0.0f;
        }
    }
}

extern "C" void kernel_launch(void* const* d_in, const int* in_sizes, int n_in,
                              void* d_out, int out_size, void* d_ws, size_t ws_size,
                              hipStream_t stream) {
    const int*   species = (const int*)  d_in[0];   // (1, N) int32
    const float* coords  = (const float*)d_in[1];   // (1, N, 3) f32
    const int*   nbr     = (const int*)  d_in[2];   // (2, P) int32
    const float* shift   = (const float*)d_in[3];   // (P, 3) f32
    float* out = (float*)d_out;                     // 6*P floats

    const int P = in_sizes[2] / 2;
    const int T = (P + 3) / 4;           // threads (4 pairs each)
    const int block = 256;
    const int grid  = (T + block - 1) / block;

    hipLaunchKernelGGL(nbr_screen_kernel, dim3(grid), dim3(block), 0, stream,
                       species, coords, nbr, shift, out, P);
}

// Round 2
// 105.167 us; speedup vs baseline: 1.2828x; 1.2828x over previous
//
#include <hip/hip_runtime.h>
#include <math.h>

// Neighborlist screening: gather -> diff -> norm -> (dummy & cutoff) mask.
// Round 2: pre-pack (x,y,z,dummy_flag) per atom into d_ws so the per-pair
// gather is 2x float4 instead of 8 scalar loads (latency/gather-bound fix).
//
// Outputs (flat float32 in d_out):
//   [0,   P)  : screened i0 as float (-1.0 if screened out)
//   [P,  2P)  : screened i1 as float
//   [2P, 3P)  : distances
//   [3P, 6P)  : diff_vectors, row-major [P][3]
#define CUTOFF_F 5.2f

__global__ __launch_bounds__(256) void pack_atoms_kernel(
    const int*   __restrict__ species,   // [N]
    const float* __restrict__ coords,    // [N*3]
    float4*      __restrict__ atoms,     // [N] packed (x,y,z,flag)
    int N)
{
    const int n = blockIdx.x * blockDim.x + threadIdx.x;
    if (n >= N) return;
    const float x = coords[3l*n], y = coords[3l*n+1], z = coords[3l*n+2];
    const float flag = (species[n] == -1) ? -1.0f : 0.0f;
    atoms[n] = make_float4(x, y, z, flag);
}

__global__ __launch_bounds__(256) void nbr_screen_packed_kernel(
    const float4* __restrict__ atoms,    // [N] packed (x,y,z,flag)
    const int*    __restrict__ nbr,      // [2*P]
    const float*  __restrict__ shift,    // [P*3]
    float*        __restrict__ out,      // [6*P]
    int P)
{
    const int t    = blockIdx.x * blockDim.x + threadIdx.x;
    const long base = (long)t * 4;
    if (base >= P) return;

    if (base + 4 <= P) {
        // ---- vectorized path: 4 pairs per thread ----
        const int4 i0v = *reinterpret_cast<const int4*>(nbr + base);
        const int4 i1v = *reinterpret_cast<const int4*>(nbr + (long)P + base);
        const float4* sv = reinterpret_cast<const float4*>(shift + base * 3);
        const float4 s0 = sv[0], s1 = sv[1], s2 = sv[2];

        const int ia[4] = {i0v.x, i0v.y, i0v.z, i0v.w};
        const int ib[4] = {i1v.x, i1v.y, i1v.z, i1v.w};

        // Issue all 8 gathers up front (max MLP before any use).
        float4 A[4], B[4];
        #pragma unroll
        for (int k = 0; k < 4; ++k) { A[k] = atoms[ia[k]]; B[k] = atoms[ib[k]]; }

        const float sh[12] = {s0.x, s0.y, s0.z, s0.w,
                              s1.x, s1.y, s1.z, s1.w,
                              s2.x, s2.y, s2.z, s2.w};

        float oi0[4], oi1[4], od[4], dv[12];
        #pragma unroll
        for (int k = 0; k < 4; ++k) {
            const bool valid = (A[k].w == 0.0f) & (B[k].w == 0.0f);
            // (c0 - c1) + shift, left-to-right like the reference
            const float dx = (A[k].x - B[k].x) + sh[3*k];
            const float dy = (A[k].y - B[k].y) + sh[3*k+1];
            const float dz = (A[k].z - B[k].z) + sh[3*k+2];
            // block fma contraction: must bit-match numpy (x*x + y*y) + z*z
            const float d2 = __fadd_rn(__fadd_rn(__fmul_rn(dx, dx),
                                                 __fmul_rn(dy, dy)),
                                       __fmul_rn(dz, dz));
            const float dist = (d2 > 0.0f) ? sqrtf(d2) : 0.0f;
            const bool keep = valid && (dist <= CUTOFF_F);
            oi0[k] = keep ? (float)ia[k] : -1.0f;
            oi1[k] = keep ? (float)ib[k] : -1.0f;
            od[k]  = keep ? dist : 0.0f;
            dv[3*k]   = keep ? dx : 0.0f;
            dv[3*k+1] = keep ? dy : 0.0f;
            dv[3*k+2] = keep ? dz : 0.0f;
        }

        *reinterpret_cast<float4*>(out + base)           = make_float4(oi0[0], oi0[1], oi0[2], oi0[3]);
        *reinterpret_cast<float4*>(out + (long)P + base) = make_float4(oi1[0], oi1[1], oi1[2], oi1[3]);
        *reinterpret_cast<float4*>(out + 2l*P + base)    = make_float4(od[0],  od[1],  od[2],  od[3]);
        float4* dvo = reinterpret_cast<float4*>(out + 3l*P + base*3);
        dvo[0] = make_float4(dv[0], dv[1], dv[2],  dv[3]);
        dvo[1] = make_float4(dv[4], dv[5], dv[6],  dv[7]);
        dvo[2] = make_float4(dv[8], dv[9], dv[10], dv[11]);
    } else {
        // ---- scalar tail (P % 4 != 0) ----
        for (long p = base; p < P; ++p) {
            const int a = nbr[p], b = nbr[(long)P + p];
            const float4 ca = atoms[a], cb = atoms[b];
            const bool valid = (ca.w == 0.0f) & (cb.w == 0.0f);
            const float dx = (ca.x - cb.x) + shift[p*3];
            const float dy = (ca.y - cb.y) + shift[p*3+1];
            const float dz = (ca.z - cb.z) + shift[p*3+2];
            const float d2 = __fadd_rn(__fadd_rn(__fmul_rn(dx, dx),
                                                 __fmul_rn(dy, dy)),
                                       __fmul_rn(dz, dz));
            const float dist = (d2 > 0.0f) ? sqrtf(d2) : 0.0f;
            const bool keep = valid && (dist <= CUTOFF_F);
            out[p]         = keep ? (float)a : -1.0f;
            out[(long)P+p] = keep ? (float)b : -1.0f;
            out[2l*P+p]    = keep ? dist : 0.0f;
            out[3l*P+p*3]   = keep ? dx : 0.0f;
            out[3l*P+p*3+1] = keep ? dy : 0.0f;
            out[3l*P+p*3+2] = keep ? dz : 0.0f;
        }
    }
}

// Fallback (no workspace): previous round's raw-gather kernel.
__global__ __launch_bounds__(256) void nbr_screen_raw_kernel(
    const int*   __restrict__ species,
    const float* __restrict__ coords,
    const int*   __restrict__ nbr,
    const float* __restrict__ shift,
    float*       __restrict__ out,
    int P)
{
    const int t = blockIdx.x * blockDim.x + threadIdx.x;
    for (long p = (long)t; p < P; p += (long)gridDim.x * blockDim.x) {
        const int a = nbr[p], b = nbr[(long)P + p];
        const bool valid = (species[a] != -1) & (species[b] != -1);
        const float dx = (coords[3l*a]   - coords[3l*b])   + shift[p*3];
        const float dy = (coords[3l*a+1] - coords[3l*b+1]) + shift[p*3+1];
        const float dz = (coords[3l*a+2] - coords[3l*b+2]) + shift[p*3+2];
        const float d2 = __fadd_rn(__fadd_rn(__fmul_rn(dx, dx),
                                             __fmul_rn(dy, dy)),
                                   __fmul_rn(dz, dz));
        const float dist = (d2 > 0.0f) ? sqrtf(d2) : 0.0f;
        const bool keep = valid && (dist <= CUTOFF_F);
        out[p]         = keep ? (float)a : -1.0f;
        out[(long)P+p] = keep ? (float)b : -1.0f;
        out[2l*P+p]    = keep ? dist : 0.0f;
        out[3l*P+p*3]   = keep ? dx : 0.0f;
        out[3l*P+p*3+1] = keep ? dy : 0.0f;
        out[3l*P+p*3+2] = keep ? dz : 0.0f;
    }
}

extern "C" void kernel_launch(void* const* d_in, const int* in_sizes, int n_in,
                              void* d_out, int out_size, void* d_ws, size_t ws_size,
                              hipStream_t stream) {
    const int*   species = (const int*)  d_in[0];   // (1, N) int32
    const float* coords  = (const float*)d_in[1];   // (1, N, 3) f32
    const int*   nbr     = (const int*)  d_in[2];   // (2, P) int32
    const float* shift   = (const float*)d_in[3];   // (P, 3) f32
    float* out = (float*)d_out;                     // 6*P floats

    const int N = in_sizes[0];
    const int P = in_sizes[2] / 2;
    const int block = 256;

    if (ws_size >= (size_t)N * sizeof(float4)) {
        float4* atoms = (float4*)d_ws;
        hipLaunchKernelGGL(pack_atoms_kernel, dim3((N + block - 1) / block),
                           dim3(block), 0, stream, species, coords, atoms, N);
        const int T = (P + 3) / 4;
        hipLaunchKernelGGL(nbr_screen_packed_kernel,
                           dim3((T + block - 1) / block), dim3(block), 0, stream,
                           atoms, nbr, shift, out, P);
    } else {
        const int grid = 2048;
        hipLaunchKernelGGL(nbr_screen_raw_kernel, dim3(grid), dim3(block), 0,
                           stream, species, coords, nbr, shift, out, P);
    }
}